// Round 1
// baseline (762.761 us; speedup 1.0000x reference)
//
#include <hip/hip_runtime.h>

#define EPSV 1e-5f

constexpr int NB = 4, CIN = 64, NH = 128, NW = 128, HID = 384, COUT = 64;
constexpr int FH = 16, FW = 16;
constexpr int N1 = HID * CIN;          // 24576
constexpr int N2 = HID * 9;            // 3456
constexpr int NP = N1 + N2 + COUT*HID; // 52608

__device__ __forceinline__ float bf2f(unsigned int lo16) {
  return __uint_as_float(lo16 << 16);
}
__device__ __forceinline__ unsigned short f2bf(float f) {
  unsigned int u = __float_as_uint(f);
  u = (u + 0x7fffu + ((u >> 16) & 1u)) >> 16;
  return (unsigned short)u;
}
__device__ __forceinline__ float clamp6(float v) {
  return fminf(fmaxf(v, 0.f), 6.f);
}

// ---------------------------------------------------------------------------
// K1: per-patch pointwise 64->384 + bn1 + relu6, h1 written as bf16.
// block = (gq, f, b*2+hh): covers 4 g-patches (32 cols) x 8 rows, 192 hids.
// 256 threads: t = hl*64 + r*8 + cg; thread owns 4 px (cols cg*4..+3), 4 hids.
// ---------------------------------------------------------------------------
__global__ __launch_bounds__(256) void k1_pw1(
    const float* __restrict__ x, const float* __restrict__ w,
    const float* __restrict__ g1, const float* __restrict__ b1,
    const float* __restrict__ m1, const float* __restrict__ v1,
    unsigned short* __restrict__ h1) {
  __shared__ unsigned short xs[CIN][8][32];   // 32 KB, bf16 x strip
  __shared__ float Wch[4][64][20];            // 20 KB, [g][cin][hid16 pad20]
  __shared__ float ivs[HID], shs[HID];        // 3 KB

  const int t  = threadIdx.x;
  const int gq = blockIdx.x;        // 0..3  (col group of 4 patches)
  const int f  = blockIdx.y;        // 0..15 (patch row)
  const int b  = blockIdx.z >> 1;
  const int hh = blockIdx.z & 1;    // hidden half (192 each)
  const int c0 = gq * 32;

  // stage x strip as bf16: [64 cin][8 rows][32 cols]
  for (int i = t; i < CIN * 256; i += 256) {
    int c = i >> 8, rr = (i >> 5) & 7, cc = i & 31;
    float v = x[(((size_t)b * CIN + c) * NH + f * 8 + rr) * NW + c0 + cc];
    xs[c][rr][cc] = f2bf(v);
  }
  for (int i = t; i < HID; i += 256) {
    float iv = g1[i] * rsqrtf(v1[i] + EPSV);
    ivs[i] = iv;
    shs[i] = b1[i] - m1[i] * iv;
  }
  __syncthreads();

  const int hl = t >> 6, r = (t >> 3) & 7, cg = t & 7;
  const int cc4 = cg * 4, gl = cg >> 1;

  for (int ch = 0; ch < 12; ++ch) {
    const int hidbase = hh * 192 + ch * 16;
    // stage 16 hids x 64 cin x 4 g of W1 (float4 over g -> coalesced-ish)
    for (int i = t; i < 1024; i += 256) {
      int hlc = i >> 6, c = i & 63;
      int p = (hidbase + hlc) * CIN + c;
      const float4 wv = *reinterpret_cast<const float4*>(
          &w[(((size_t)b * NP + p) * FH + f) * FW + gq * 4]);
      Wch[0][c][hlc] = wv.x; Wch[1][c][hlc] = wv.y;
      Wch[2][c][hlc] = wv.z; Wch[3][c][hlc] = wv.w;
    }
    __syncthreads();

    float acc[4][4];
#pragma unroll
    for (int j = 0; j < 4; ++j)
#pragma unroll
      for (int k = 0; k < 4; ++k) acc[j][k] = 0.f;

#pragma unroll 8
    for (int c = 0; c < CIN; ++c) {
      const float4 wv = *reinterpret_cast<const float4*>(&Wch[gl][c][hl * 4]);
      const ushort4 xv = *reinterpret_cast<const ushort4*>(&xs[c][r][cc4]);
      float xf[4] = {bf2f(xv.x), bf2f(xv.y), bf2f(xv.z), bf2f(xv.w)};
      float wf[4] = {wv.x, wv.y, wv.z, wv.w};
#pragma unroll
      for (int j = 0; j < 4; ++j)
#pragma unroll
        for (int k = 0; k < 4; ++k) acc[j][k] += wf[j] * xf[k];
    }

#pragma unroll
    for (int j = 0; j < 4; ++j) {
      const int hid = hidbase + hl * 4 + j;
      const float iv = ivs[hid], sh = shs[hid];
      ushort4 o;
      o.x = f2bf(clamp6(acc[j][0] * iv + sh));
      o.y = f2bf(clamp6(acc[j][1] * iv + sh));
      o.z = f2bf(clamp6(acc[j][2] * iv + sh));
      o.w = f2bf(clamp6(acc[j][3] * iv + sh));
      *reinterpret_cast<ushort4*>(
          &h1[(((size_t)b * HID + hid) * NH + f * 8 + r) * NW + c0 + cc4]) = o;
    }
    __syncthreads();
  }
}

// ---------------------------------------------------------------------------
// K2: fused dw3(reflect halo) + bn2 + relu6 + pw2 + bn3 + residual.
// block = (gq, f, b*2+chf): 4 g-patches x 8 rows, 32 of 64 out channels.
// 256 threads: thread owns 4 px, 8 co; per 32-hid chunk computes h2 in LDS.
// ---------------------------------------------------------------------------
__global__ __launch_bounds__(256) void k2_fused(
    const float* __restrict__ x, const float* __restrict__ w,
    const float* __restrict__ g2, const float* __restrict__ b2v,
    const float* __restrict__ m2, const float* __restrict__ v2,
    const float* __restrict__ g3, const float* __restrict__ b3v,
    const float* __restrict__ m3, const float* __restrict__ v3,
    const unsigned short* __restrict__ h1, float* __restrict__ out) {
  __shared__ unsigned short tile[32][10][36];  // 23.0 KB h1 halo tile (bf16)
  __shared__ unsigned short h2s[32][8][32];    // 16 KB h2 chunk (bf16)
  __shared__ unsigned short W3s[4][32][40];    // 10.2 KB [g][hid][co pad40]
  __shared__ float k2s[32][9][4];              // 4.6 KB dw kernels [hid][tap][g]
  __shared__ float iv2s[HID], sh2s[HID];       // 3 KB

  const int t   = threadIdx.x;
  const int gq  = blockIdx.x, f = blockIdx.y;
  const int b   = blockIdx.z >> 1, chf = blockIdx.z & 1;
  const int c0  = gq * 32;

  for (int i = t; i < HID; i += 256) {
    float iv = g2[i] * rsqrtf(v2[i] + EPSV);
    iv2s[i] = iv;
    sh2s[i] = b2v[i] - m2[i] * iv;
  }

  const int hl = t >> 6, r = (t >> 3) & 7, cg = t & 7;
  const int cc4 = cg * 4, gl = cg >> 1;

  float iv3[8], sh3[8];
#pragma unroll
  for (int j = 0; j < 8; ++j) {
    int co = chf * 32 + hl * 8 + j;
    float iv = g3[co] * rsqrtf(v3[co] + EPSV);
    iv3[j] = iv;
    sh3[j] = b3v[co] - m3[co] * iv;
  }

  float acc[8][4];
#pragma unroll
  for (int j = 0; j < 8; ++j)
#pragma unroll
    for (int k = 0; k < 4; ++k) acc[j][k] = 0.f;

  for (int hc = 0; hc < 12; ++hc) {
    const int hb = hc * 32;
    __syncthreads();  // protects tile/k2s/W3s (read last iter) and iv2s (first)

    // h1 halo tile: rows f*8-1..f*8+8, cols c0-1..c0+32 with full-map reflect
    for (int i = t; i < 32 * 340; i += 256) {
      int hid_l = i / 340, rem = i - hid_l * 340;
      int tr = rem / 34, tc = rem - tr * 34;
      int y = f * 8 - 1 + tr;
      y = (y < 0) ? -y : ((y > 127) ? 254 - y : y);
      int xc = c0 - 1 + tc;
      xc = (xc < 0) ? -xc : ((xc > 127) ? 254 - xc : xc);
      tile[hid_l][tr][tc] =
          h1[(((size_t)b * HID + hb + hid_l) * NH + y) * NW + xc];
    }
    // dw kernels for this hid chunk (float4 over g)
    for (int i = t; i < 288; i += 256) {
      int hid_l = i / 9, tap = i - hid_l * 9;
      int p = N1 + (hb + hid_l) * 9 + tap;
      const float4 wv = *reinterpret_cast<const float4*>(
          &w[(((size_t)b * NP + p) * FH + f) * FW + gq * 4]);
      k2s[hid_l][tap][0] = wv.x; k2s[hid_l][tap][1] = wv.y;
      k2s[hid_l][tap][2] = wv.z; k2s[hid_l][tap][3] = wv.w;
    }
    // W3 chunk: [g][hid32][co32] bf16 (float4 over g)
    for (int i = t; i < 1024; i += 256) {
      int co_l = i >> 5, hh2 = i & 31;
      int p = N1 + N2 + (chf * 32 + co_l) * HID + hb + hh2;
      const float4 wv = *reinterpret_cast<const float4*>(
          &w[(((size_t)b * NP + p) * FH + f) * FW + gq * 4]);
      W3s[0][hh2][co_l] = f2bf(wv.x); W3s[1][hh2][co_l] = f2bf(wv.y);
      W3s[2][hh2][co_l] = f2bf(wv.z); W3s[3][hh2][co_l] = f2bf(wv.w);
    }
    __syncthreads();

    // dw3 + bn2 + relu6 -> h2s (thread: 8 hids x its 4 px)
#pragma unroll
    for (int j = 0; j < 8; ++j) {
      const int hid_l = hl * 8 + j;
      const int hid = hb + hid_l;
      float kk[9];
#pragma unroll
      for (int tap = 0; tap < 9; ++tap) kk[tap] = k2s[hid_l][tap][gl];
      float d0 = 0.f, d1 = 0.f, d2 = 0.f, d3 = 0.f;
#pragma unroll
      for (int dy = 0; dy < 3; ++dy) {
        const uint2 a =
            *reinterpret_cast<const uint2*>(&tile[hid_l][r + dy][cc4]);
        const unsigned int bq =
            *reinterpret_cast<const unsigned int*>(&tile[hid_l][r + dy][cc4 + 4]);
        float tv[6];
        tv[0] = __uint_as_float(a.x << 16);
        tv[1] = __uint_as_float(a.x & 0xffff0000u);
        tv[2] = __uint_as_float(a.y << 16);
        tv[3] = __uint_as_float(a.y & 0xffff0000u);
        tv[4] = __uint_as_float(bq << 16);
        tv[5] = __uint_as_float(bq & 0xffff0000u);
#pragma unroll
        for (int dx = 0; dx < 3; ++dx) {
          const float k = kk[dy * 3 + dx];
          d0 += k * tv[dx];
          d1 += k * tv[dx + 1];
          d2 += k * tv[dx + 2];
          d3 += k * tv[dx + 3];
        }
      }
      const float iv = iv2s[hid], sh = sh2s[hid];
      ushort4 o;
      o.x = f2bf(clamp6(d0 * iv + sh));
      o.y = f2bf(clamp6(d1 * iv + sh));
      o.z = f2bf(clamp6(d2 * iv + sh));
      o.w = f2bf(clamp6(d3 * iv + sh));
      *reinterpret_cast<ushort4*>(&h2s[hid_l][r][cc4]) = o;
    }
    __syncthreads();

    // pw2 partial accumulation over this hid chunk
#pragma unroll 8
    for (int hh2 = 0; hh2 < 32; ++hh2) {
      const uint2 hu = *reinterpret_cast<const uint2*>(&h2s[hh2][r][cc4]);
      float hv[4];
      hv[0] = __uint_as_float(hu.x << 16);
      hv[1] = __uint_as_float(hu.x & 0xffff0000u);
      hv[2] = __uint_as_float(hu.y << 16);
      hv[3] = __uint_as_float(hu.y & 0xffff0000u);
      const uint4 wu = *reinterpret_cast<const uint4*>(&W3s[gl][hh2][hl * 8]);
      float wv[8];
      wv[0] = __uint_as_float(wu.x << 16);
      wv[1] = __uint_as_float(wu.x & 0xffff0000u);
      wv[2] = __uint_as_float(wu.y << 16);
      wv[3] = __uint_as_float(wu.y & 0xffff0000u);
      wv[4] = __uint_as_float(wu.z << 16);
      wv[5] = __uint_as_float(wu.z & 0xffff0000u);
      wv[6] = __uint_as_float(wu.w << 16);
      wv[7] = __uint_as_float(wu.w & 0xffff0000u);
#pragma unroll
      for (int j = 0; j < 8; ++j)
#pragma unroll
        for (int k = 0; k < 4; ++k) acc[j][k] += wv[j] * hv[k];
    }
  }

  // epilogue: bn3 + residual, float4 stores
  const int y = f * 8 + r;
#pragma unroll
  for (int j = 0; j < 8; ++j) {
    const int co = chf * 32 + hl * 8 + j;
    const size_t base = (((size_t)b * COUT + co) * NH + y) * NW + c0 + cc4;
    const float4 xr = *reinterpret_cast<const float4*>(&x[base]);
    float4 o;
    o.x = acc[j][0] * iv3[j] + sh3[j] + xr.x;
    o.y = acc[j][1] * iv3[j] + sh3[j] + xr.y;
    o.z = acc[j][2] * iv3[j] + sh3[j] + xr.z;
    o.w = acc[j][3] * iv3[j] + sh3[j] + xr.w;
    *reinterpret_cast<float4*>(&out[base]) = o;
  }
}

extern "C" void kernel_launch(void* const* d_in, const int* in_sizes, int n_in,
                              void* d_out, int out_size, void* d_ws,
                              size_t ws_size, hipStream_t stream) {
  const float* x  = (const float*)d_in[0];
  const float* w  = (const float*)d_in[1];
  const float* g1 = (const float*)d_in[2];
  const float* b1 = (const float*)d_in[3];
  const float* m1 = (const float*)d_in[4];
  const float* v1 = (const float*)d_in[5];
  const float* g2 = (const float*)d_in[6];
  const float* b2 = (const float*)d_in[7];
  const float* m2 = (const float*)d_in[8];
  const float* v2 = (const float*)d_in[9];
  const float* g3 = (const float*)d_in[10];
  const float* b3 = (const float*)d_in[11];
  const float* m3 = (const float*)d_in[12];
  const float* v3 = (const float*)d_in[13];
  float* out = (float*)d_out;
  unsigned short* h1 = (unsigned short*)d_ws;  // 4*384*128*128 bf16 = 50.3 MB

  dim3 blk(256);
  dim3 grid(4, 16, 8);
  k1_pw1<<<grid, blk, 0, stream>>>(x, w, g1, b1, m1, v1, h1);
  k2_fused<<<grid, blk, 0, stream>>>(x, w, g2, b2, m2, v2, g3, b3, m3, v3, h1,
                                     out);
}

// Round 2
// 548.615 us; speedup vs baseline: 1.3903x; 1.3903x over previous
//
#include <hip/hip_runtime.h>

#define EPSV 1e-5f

constexpr int CIN = 64, NH = 128, NW = 128, HID = 384, COUT = 64;
constexpr int N1 = HID * CIN;            // 24576
constexpr int N2 = HID * 9;              // 3456
constexpr int NP = N1 + N2 + COUT * HID; // 52608

using bf16x8 = __attribute__((ext_vector_type(8))) short;
using f32x4  = __attribute__((ext_vector_type(4))) float;

__device__ __forceinline__ unsigned short f2bf(float f) {
  unsigned int u = __float_as_uint(f);
  u = (u + 0x7fffu + ((u >> 16) & 1u)) >> 16;
  return (unsigned short)u;
}
__device__ __forceinline__ float ulo(unsigned int u) { return __uint_as_float(u << 16); }
__device__ __forceinline__ float uhi(unsigned int u) { return __uint_as_float(u & 0xffff0000u); }
__device__ __forceinline__ float clamp6(float v) { return fminf(fmaxf(v, 0.f), 6.f); }

// ---------------------------------------------------------------------------
// K1: per-patch pw1 (MFMA 16x16x32 bf16) + bn1 + relu6 -> h1 (bf16).
// block=(hgrp 0..23, f, b): 16 hids x all 16 g-patches. W1 read as full lines.
// Wpk holds ready A-fragments: unit (g,kc,quad,hid') of 8 bf16,
// hid' = hid ^ (2*quad) ^ (g>>2)  (bank swizzle for staging writes).
// ---------------------------------------------------------------------------
__global__ __launch_bounds__(256) void k1_pw1(
    const float* __restrict__ x, const float* __restrict__ w,
    const float* __restrict__ g1, const float* __restrict__ b1,
    const float* __restrict__ m1, const float* __restrict__ v1,
    unsigned short* __restrict__ h1) {
  __shared__ unsigned short Wpk[16 * 2 * 64 * 8];  // 32 KB packed A-frags
  __shared__ unsigned short xls[64][66];           // 8.25 KB bf16 [c][px]

  const int t = threadIdx.x;
  const int hgrp = blockIdx.x, f = blockIdx.y, b = blockIdx.z;
  const int h0 = hgrp * 16;
  const int lane = t & 63, wvid = t >> 6;
  const int quad = lane >> 4, nn = lane & 15;
  const int pxi = wvid * 16 + nn;  // px within patch for this lane's B column

  // ---- stage Wpk: 16 hid x 64 c x 16 g (full-line reads: 4 lanes = 1 line) --
#pragma unroll
  for (int it = 0; it < 16; ++it) {
    int i = it * 256 + t;
    int gq = i & 3, c = (i >> 2) & 63, hid = i >> 8;
    const float4 wv = *reinterpret_cast<const float4*>(
        &w[(size_t)(b * NP + (h0 + hid) * CIN + c) * 256 + f * 16 + gq * 4]);
    int kc = c >> 5, qd = (c >> 3) & 3, j = c & 7;
    int hs = hid ^ (2 * qd) ^ gq;
    float arr[4] = {wv.x, wv.y, wv.z, wv.w};
#pragma unroll
    for (int k = 0; k < 4; ++k) {
      int g = gq * 4 + k;
      Wpk[(((g * 2 + kc) * 4 + qd) * 16 + hs) * 8 + j] = f2bf(arr[k]);
    }
  }

  // per-lane bn consts for the 4 output rows (hid = h0 + quad*4 + jj)
  float iv1[4], sh1[4];
#pragma unroll
  for (int jj = 0; jj < 4; ++jj) {
    int hid = h0 + quad * 4 + jj;
    float iv = g1[hid] * rsqrtf(v1[hid] + EPSV);
    iv1[jj] = iv;
    sh1[jj] = b1[hid] - m1[hid] * iv;
  }

  // preload x for patch 0 into registers
  float4 pf[4];
#pragma unroll
  for (int it = 0; it < 4; ++it) {
    int i = it * 256 + t;
    int c = i >> 4, r = (i >> 1) & 7, cq = i & 1;
    pf[it] = *reinterpret_cast<const float4*>(
        &x[(size_t)((b * CIN + c) * NH + f * 8 + r) * NW + cq * 4]);
  }
  __syncthreads();  // Wpk ready

  for (int g = 0; g < 16; ++g) {
    // write staged x regs to xls (bf16, ushort2 writes)
#pragma unroll
    for (int it = 0; it < 4; ++it) {
      int i = it * 256 + t;
      int c = i >> 4, r = (i >> 1) & 7, cq = i & 1;
      int px = r * 8 + cq * 4;
      *(unsigned int*)&xls[c][px] =
          (unsigned int)f2bf(pf[it].x) | ((unsigned int)f2bf(pf[it].y) << 16);
      *(unsigned int*)&xls[c][px + 2] =
          (unsigned int)f2bf(pf[it].z) | ((unsigned int)f2bf(pf[it].w) << 16);
    }
    __syncthreads();
    // prefetch next patch
    if (g < 15) {
#pragma unroll
      for (int it = 0; it < 4; ++it) {
        int i = it * 256 + t;
        int c = i >> 4, r = (i >> 1) & 7, cq = i & 1;
        pf[it] = *reinterpret_cast<const float4*>(
            &x[(size_t)((b * CIN + c) * NH + f * 8 + r) * NW + (g + 1) * 8 +
               cq * 4]);
      }
    }
    // MFMA: h1_tile[16 hid][16 px] += W1[16x32] @ x[32x16], 2 K-steps
    f32x4 acc = {0.f, 0.f, 0.f, 0.f};
#pragma unroll
    for (int kc = 0; kc < 2; ++kc) {
      int hs = nn ^ (2 * quad) ^ (g >> 2);
      bf16x8 af = *reinterpret_cast<const bf16x8*>(
          &Wpk[(((g * 2 + kc) * 4 + quad) * 16 + hs) * 8]);
      bf16x8 bf;
#pragma unroll
      for (int j = 0; j < 8; ++j)
        bf[j] = (short)xls[kc * 32 + quad * 8 + j][pxi];
      acc = __builtin_amdgcn_mfma_f32_16x16x32_bf16(af, bf, acc, 0, 0, 0);
    }
    // epilogue: bn1 + relu6 -> h1 bf16
    int y = f * 8 + (pxi >> 3), xc = g * 8 + (pxi & 7);
#pragma unroll
    for (int jj = 0; jj < 4; ++jj) {
      int hid = h0 + quad * 4 + jj;
      h1[(size_t)((b * HID + hid) * NH + y) * NW + xc] =
          f2bf(clamp6(acc[jj] * iv1[jj] + sh1[jj]));
    }
    __syncthreads();  // xls consumed; safe to overwrite next iter
  }
}

// ---------------------------------------------------------------------------
// K2: dw3(reflect halo, VALU) + bn2 + relu6 + pw2 (MFMA) + bn3 + residual.
// block=(gq*2+ch, f, b): 4 patches (32 cols x 8 rows = 256 px), 32 co.
// Loop over 12 hid-chunks of 32: stage h1 halo tile [row][col][hid],
// dw weights, W3 frags; dw3 -> h2s [px][hid] (B-frag order); MFMA accumulate.
// ---------------------------------------------------------------------------
__global__ __launch_bounds__(256) void k2_fused(
    const float* __restrict__ x, const float* __restrict__ w,
    const float* __restrict__ g2, const float* __restrict__ b2v,
    const float* __restrict__ m2, const float* __restrict__ v2,
    const float* __restrict__ g3, const float* __restrict__ b3v,
    const float* __restrict__ m3, const float* __restrict__ v3,
    const unsigned short* __restrict__ h1, float* __restrict__ out) {
  __shared__ unsigned short tile[10][34][40];    // 27.2 KB h1 halo (bf16)
  __shared__ unsigned short h2s[256][40];        // 20.5 KB h2 chunk [px][hid]
  __shared__ unsigned short W3p[4 * 2 * 64 * 8]; // 8 KB packed A-frags
  __shared__ unsigned short k2w[4][9][40];       // 2.9 KB dw kernels [gl][tap][hid]
  __shared__ float iv2s[HID], sh2s[HID];         // 3 KB

  const int t = threadIdx.x;
  const int gq = blockIdx.x >> 1, ch = blockIdx.x & 1;
  const int f = blockIdx.y, b = blockIdx.z;
  const int c0 = gq * 32;
  const int lane = t & 63, wv = t >> 6;
  const int quad = lane >> 4, nn = lane & 15;

  for (int i = t; i < HID; i += 256) {
    float iv = g2[i] * rsqrtf(v2[i] + EPSV);
    iv2s[i] = iv;
    sh2s[i] = b2v[i] - m2[i] * iv;
  }

  float iv3[2][4], sh3[2][4];
#pragma unroll
  for (int cot = 0; cot < 2; ++cot)
#pragma unroll
    for (int jj = 0; jj < 4; ++jj) {
      int co = ch * 32 + cot * 16 + quad * 4 + jj;
      float iv = g3[co] * rsqrtf(v3[co] + EPSV);
      iv3[cot][jj] = iv;
      sh3[cot][jj] = b3v[co] - m3[co] * iv;
    }

  f32x4 acc[2][4];
#pragma unroll
  for (int cot = 0; cot < 2; ++cot)
#pragma unroll
    for (int nt = 0; nt < 4; ++nt) acc[cot][nt] = (f32x4){0.f, 0.f, 0.f, 0.f};

  // dw3 thread mapping: 1 px x 32 hid; px index space = gl*64 + r*8 + c
  const int glt = t >> 6, rt = (t >> 3) & 7, ct = t & 7;

  for (int hc = 0; hc < 12; ++hc) {
    const int hb = hc * 32;
    __syncthreads();  // prev chunk's pw2 done with h2s/W3p; tile reusable

    // ---- stage h1 halo tile: rows f*8-1..+8, cols c0-1..c0+32 (reflect) ----
    {
      const int cq = t & 7, hh = t >> 3;  // hh 0..31
      const unsigned short* h1b =
          h1 + (size_t)(b * HID + hb + hh) * (NH * NW);
#pragma unroll
      for (int r = 0; r < 10; ++r) {
        int y = f * 8 - 1 + r;
        y = (y < 0) ? -y : ((y > 127) ? 254 - y : y);
        const unsigned short* rowp = h1b + y * NW;
        ushort4 vv = *reinterpret_cast<const ushort4*>(&rowp[c0 + cq * 4]);
        tile[r][1 + cq * 4 + 0][hh] = vv.x;
        tile[r][1 + cq * 4 + 1][hh] = vv.y;
        tile[r][1 + cq * 4 + 2][hh] = vv.z;
        tile[r][1 + cq * 4 + 3][hh] = vv.w;
        if (cq == 0) tile[r][0][hh] = rowp[(c0 == 0) ? 1 : c0 - 1];
        if (cq == 7) tile[r][33][hh] = rowp[(c0 + 32 > 127) ? 126 : c0 + 32];
      }
    }
    // ---- stage dw kernels (float4 over g -> the block's 4 patches) ----
    for (int i = t; i < 288; i += 256) {
      int hh = i / 9, tap = i - hh * 9;
      const float4 wv4 = *reinterpret_cast<const float4*>(
          &w[(size_t)(b * NP + N1 + (hb + hh) * 9 + tap) * 256 + f * 16 +
             gq * 4]);
      k2w[0][tap][hh] = f2bf(wv4.x);
      k2w[1][tap][hh] = f2bf(wv4.y);
      k2w[2][tap][hh] = f2bf(wv4.z);
      k2w[3][tap][hh] = f2bf(wv4.w);
    }
    // ---- stage W3 chunk as packed A-frags (swizzled) ----
#pragma unroll
    for (int it = 0; it < 4; ++it) {
      int i = it * 256 + t;
      int hh = i & 31, co = i >> 5;  // co 0..31 (local to ch half)
      const float4 wv4 = *reinterpret_cast<const float4*>(
          &w[(size_t)(b * NP + N1 + N2 + (ch * 32 + co) * HID + hb + hh) * 256 +
             f * 16 + gq * 4]);
      int qd = hh >> 3, j = hh & 7, cot = co >> 4;
      float arr[4] = {wv4.x, wv4.y, wv4.z, wv4.w};
#pragma unroll
      for (int k = 0; k < 4; ++k) {
        int cop = (co & 15) ^ (2 * qd) ^ k;
        W3p[(((k * 2 + cot) * 4 + qd) * 16 + cop) * 8 + j] = f2bf(arr[k]);
      }
    }
    __syncthreads();

    // ---- dw3 + bn2 + relu6 -> h2s (thread: 1 px, 32 hids) ----
#pragma unroll
    for (int hg = 0; hg < 4; ++hg) {
      float d[8] = {0.f, 0.f, 0.f, 0.f, 0.f, 0.f, 0.f, 0.f};
#pragma unroll
      for (int dy = 0; dy < 3; ++dy)
#pragma unroll
        for (int dx = 0; dx < 3; ++dx) {
          const uint4 tv =
              *reinterpret_cast<const uint4*>(&tile[rt + dy][glt * 8 + ct + dx][hg * 8]);
          const uint4 kv =
              *reinterpret_cast<const uint4*>(&k2w[glt][dy * 3 + dx][hg * 8]);
          d[0] += ulo(tv.x) * ulo(kv.x); d[1] += uhi(tv.x) * uhi(kv.x);
          d[2] += ulo(tv.y) * ulo(kv.y); d[3] += uhi(tv.y) * uhi(kv.y);
          d[4] += ulo(tv.z) * ulo(kv.z); d[5] += uhi(tv.z) * uhi(kv.z);
          d[6] += ulo(tv.w) * ulo(kv.w); d[7] += uhi(tv.w) * uhi(kv.w);
        }
      uint4 o4;
      unsigned int op[4];
#pragma unroll
      for (int j2 = 0; j2 < 4; ++j2) {
        int ha = hb + hg * 8 + j2 * 2;
        float oa = clamp6(d[j2 * 2] * iv2s[ha] + sh2s[ha]);
        float ob = clamp6(d[j2 * 2 + 1] * iv2s[ha + 1] + sh2s[ha + 1]);
        op[j2] = (unsigned int)f2bf(oa) | ((unsigned int)f2bf(ob) << 16);
      }
      o4.x = op[0]; o4.y = op[1]; o4.z = op[2]; o4.w = op[3];
      *reinterpret_cast<uint4*>(&h2s[t][hg * 8]) = o4;
    }
    __syncthreads();

    // ---- pw2 MFMA accumulate over this 32-hid chunk (wave = patch gl) ----
    {
      const int gl = wv;
      const int cop = nn ^ (2 * quad) ^ gl;
      bf16x8 a0 = *reinterpret_cast<const bf16x8*>(
          &W3p[(((gl * 2 + 0) * 4 + quad) * 16 + cop) * 8]);
      bf16x8 a1 = *reinterpret_cast<const bf16x8*>(
          &W3p[(((gl * 2 + 1) * 4 + quad) * 16 + cop) * 8]);
#pragma unroll
      for (int nt = 0; nt < 4; ++nt) {
        bf16x8 bfr = *reinterpret_cast<const bf16x8*>(
            &h2s[gl * 64 + nt * 16 + nn][quad * 8]);
        acc[0][nt] = __builtin_amdgcn_mfma_f32_16x16x32_bf16(a0, bfr, acc[0][nt], 0, 0, 0);
        acc[1][nt] = __builtin_amdgcn_mfma_f32_16x16x32_bf16(a1, bfr, acc[1][nt], 0, 0, 0);
      }
    }
  }

  // ---- epilogue: bn3 + residual ----
#pragma unroll
  for (int cot = 0; cot < 2; ++cot)
#pragma unroll
    for (int nt = 0; nt < 4; ++nt) {
      int pxl = nt * 16 + nn;
      int y = f * 8 + (pxl >> 3);
      int xc = c0 + wv * 8 + (pxl & 7);
#pragma unroll
      for (int jj = 0; jj < 4; ++jj) {
        int co = ch * 32 + cot * 16 + quad * 4 + jj;
        size_t adr = ((size_t)(b * COUT + co) * NH + y) * NW + xc;
        out[adr] = acc[cot][nt][jj] * iv3[cot][jj] + sh3[cot][jj] + x[adr];
      }
    }
}

extern "C" void kernel_launch(void* const* d_in, const int* in_sizes, int n_in,
                              void* d_out, int out_size, void* d_ws,
                              size_t ws_size, hipStream_t stream) {
  (void)in_sizes; (void)n_in; (void)out_size; (void)ws_size;
  const float* x  = (const float*)d_in[0];
  const float* w  = (const float*)d_in[1];
  const float* g1 = (const float*)d_in[2];
  const float* b1 = (const float*)d_in[3];
  const float* m1 = (const float*)d_in[4];
  const float* v1 = (const float*)d_in[5];
  const float* g2 = (const float*)d_in[6];
  const float* b2 = (const float*)d_in[7];
  const float* m2 = (const float*)d_in[8];
  const float* v2 = (const float*)d_in[9];
  const float* g3 = (const float*)d_in[10];
  const float* b3 = (const float*)d_in[11];
  const float* m3 = (const float*)d_in[12];
  const float* v3 = (const float*)d_in[13];
  float* out = (float*)d_out;
  unsigned short* h1 = (unsigned short*)d_ws;  // 4*384*128*128 bf16 = 50.3 MB

  k1_pw1<<<dim3(24, 16, 4), 256, 0, stream>>>(x, w, g1, b1, m1, v1, h1);
  k2_fused<<<dim3(8, 16, 4), 256, 0, stream>>>(x, w, g2, b2, m2, v2, g3, b3,
                                               m3, v3, h1, out);
}

// Round 4
// 460.795 us; speedup vs baseline: 1.6553x; 1.1906x over previous
//
#include <hip/hip_runtime.h>

#define EPSV 1e-5f

constexpr int CIN = 64, NH = 128, NW = 128, HID = 384, COUT = 64;
constexpr int N1 = HID * CIN;            // 24576
constexpr int N2 = HID * 9;              // 3456
constexpr int NP = N1 + N2 + COUT * HID; // 52608

using bf16x8 = __attribute__((ext_vector_type(8))) short;
using f32x4  = __attribute__((ext_vector_type(4))) float;

__device__ __forceinline__ unsigned short f2bf(float f) {
  unsigned int u = __float_as_uint(f);
  u = (u + 0x7fffu + ((u >> 16) & 1u)) >> 16;
  return (unsigned short)u;
}
__device__ __forceinline__ unsigned int pack2(float a, float b) {
  return (unsigned int)f2bf(a) | ((unsigned int)f2bf(b) << 16);
}
__device__ __forceinline__ float ulo(unsigned int u) { return __uint_as_float(u << 16); }
__device__ __forceinline__ float uhi(unsigned int u) { return __uint_as_float(u & 0xffff0000u); }
__device__ __forceinline__ float clamp6(float v) { return fminf(fmaxf(v, 0.f), 6.f); }

// ---------------------------------------------------------------------------
// K0: transpose x [b][c][y][x] f32 -> xT [b][y][x][c] bf16 (8.4 MB, in d_out).
// ---------------------------------------------------------------------------
__global__ __launch_bounds__(256) void k0_transpose(
    const float* __restrict__ x, unsigned short* __restrict__ xT) {
  __shared__ unsigned short xls[64][66];
  const int t = threadIdx.x;
  const int xh = blockIdx.x, y = blockIdx.y, b = blockIdx.z;
#pragma unroll
  for (int it = 0; it < 4; ++it) {
    int i = it * 256 + t;
    int xq = i & 15, c = i >> 4;
    float4 v = *reinterpret_cast<const float4*>(
        &x[((size_t)(b * CIN + c) * NH + y) * NW + xh * 64 + xq * 4]);
    *(unsigned int*)&xls[c][xq * 4]     = pack2(v.x, v.y);
    *(unsigned int*)&xls[c][xq * 4 + 2] = pack2(v.z, v.w);
  }
  __syncthreads();
#pragma unroll
  for (int it = 0; it < 4; ++it) {
    int i = it * 256 + t;
    int cq = i & 15, px = i >> 4;
    ushort4 o;
    o.x = xls[cq * 4 + 0][px];
    o.y = xls[cq * 4 + 1][px];
    o.z = xls[cq * 4 + 2][px];
    o.w = xls[cq * 4 + 3][px];
    *reinterpret_cast<ushort4*>(
        &xT[((size_t)(b * NH + y) * NW + xh * 64 + px) * 64 + cq * 4]) = o;
  }
}

// ---------------------------------------------------------------------------
// K1: per-patch pw1 (MFMA) + bn1 + relu6 -> h1T [b][y][x][hid] bf16.
// 1-D grid 1536, XCD-swizzled: all 24 hgrp blocks of one (f,b) strip share
// linear%8 (same XCD) -> xT strip stays in that XCD's L2.
// No syncthreads in the g-loop: B-frags load straight from xT (global b128).
// ---------------------------------------------------------------------------
__global__ __launch_bounds__(256) void k1_pw1(
    const float* __restrict__ w, const unsigned short* __restrict__ xT,
    const float* __restrict__ g1, const float* __restrict__ b1,
    const float* __restrict__ m1, const float* __restrict__ v1,
    unsigned short* __restrict__ h1T) {
  __shared__ unsigned short Wpk[2048 * 8];  // 32 KB packed A-frags

  const unsigned int id = blockIdx.x;
  const int fbq = id & 7;
  const unsigned int rest = id >> 3;
  const int hgrp = rest % 24, q = rest / 24;
  const int fb = q * 8 + fbq;
  const int f = fb & 15, b = fb >> 4;
  const int h0 = hgrp * 16;

  const int t = threadIdx.x;
  const int lane = t & 63, wv = t >> 6;
  const int quad = lane >> 4, nn = lane & 15;
  const int pxi = wv * 16 + nn;

  // ---- stage Wpk: 16 hid x 64 c x 16 g, c-paired u32 LDS writes ----
#pragma unroll
  for (int it = 0; it < 8; ++it) {
    int i = it * 256 + t;  // 0..2047
    int gq = i & 3, cp = (i >> 2) & 31, hid = i >> 7;
    const float* wp =
        &w[((size_t)b * NP + (h0 + hid) * CIN + cp * 2) * 256 + f * 16 + gq * 4];
    float4 A  = *reinterpret_cast<const float4*>(wp);
    float4 Bv = *reinterpret_cast<const float4*>(wp + 256);
    int kc = cp >> 4, qd = (cp >> 2) & 3, j = (cp & 3) * 2;
    int hs = hid ^ (2 * qd) ^ gq;
    const float* Af = (const float*)&A;
    const float* Bf = (const float*)&Bv;
#pragma unroll
    for (int k = 0; k < 4; ++k) {
      int g = gq * 4 + k;
      *(unsigned int*)&Wpk[(((g * 2 + kc) * 4 + qd) * 16 + hs) * 8 + j] =
          pack2(Af[k], Bf[k]);
    }
  }

  float iv1[4], sh1[4];
#pragma unroll
  for (int jj = 0; jj < 4; ++jj) {
    int hid = h0 + quad * 4 + jj;
    float iv = g1[hid] * rsqrtf(v1[hid] + EPSV);
    iv1[jj] = iv;
    sh1[jj] = b1[hid] - m1[hid] * iv;
  }
  __syncthreads();  // Wpk ready; read-only below

  const int y = f * 8 + (pxi >> 3);
  const size_t rowbase = ((size_t)b * NH + y) * NW;

  for (int g = 0; g < 16; ++g) {
    const int xc = g * 8 + (pxi & 7);
    const unsigned short* xp = &xT[(rowbase + xc) * 64];
    f32x4 acc = {0.f, 0.f, 0.f, 0.f};
    const int hs = nn ^ (2 * quad) ^ (g >> 2);
#pragma unroll
    for (int kc = 0; kc < 2; ++kc) {
      bf16x8 af = *reinterpret_cast<const bf16x8*>(
          &Wpk[(((g * 2 + kc) * 4 + quad) * 16 + hs) * 8]);
      bf16x8 bfr = *reinterpret_cast<const bf16x8*>(&xp[kc * 32 + quad * 8]);
      acc = __builtin_amdgcn_mfma_f32_16x16x32_bf16(af, bfr, acc, 0, 0, 0);
    }
    ushort4 o;
    o.x = f2bf(clamp6(acc[0] * iv1[0] + sh1[0]));
    o.y = f2bf(clamp6(acc[1] * iv1[1] + sh1[1]));
    o.z = f2bf(clamp6(acc[2] * iv1[2] + sh1[2]));
    o.w = f2bf(clamp6(acc[3] * iv1[3] + sh1[3]));
    *reinterpret_cast<ushort4*>(&h1T[(rowbase + xc) * HID + h0 + quad * 4]) = o;
  }
}

// ---------------------------------------------------------------------------
// K2: dw3(reflect halo, VALU) + bn2 + relu6 + pw2 (MFMA) + bn3 + residual.
// 1-D grid 512, XCD-swizzled: the 8 blocks (4 gq x 2 ch) of one (f,b) share
// linear%8 -> W3/N2 quarter-line reads combine in that XCD's L2.
// h1T layout [b][y][x][hid] -> halo staging is line-exact 16-B loads.
// ---------------------------------------------------------------------------
__global__ __launch_bounds__(256) void k2_fused(
    const float* __restrict__ x, const float* __restrict__ w,
    const float* __restrict__ g2, const float* __restrict__ b2v,
    const float* __restrict__ m2, const float* __restrict__ v2,
    const float* __restrict__ g3, const float* __restrict__ b3v,
    const float* __restrict__ m3, const float* __restrict__ v3,
    const unsigned short* __restrict__ h1T, float* __restrict__ out) {
  __shared__ unsigned short tile[10][34][40];  // 27.2 KB h1 halo [r][col][hid]
  __shared__ unsigned short h2s[256][40];      // 20.5 KB h2 chunk [px][hid]
  __shared__ unsigned short W3p[512 * 8];      // 8 KB packed A-frags
  __shared__ unsigned short k2w[4][9][40];     // 2.9 KB dw kernels [g][tap][hid]
  __shared__ float iv2s[HID], sh2s[HID];       // 3 KB

  const unsigned int id = blockIdx.x;
  const int fbq = id & 7;
  const unsigned int rest = id >> 3;
  const int gang = rest & 7, q = rest >> 3;
  const int fb = q * 8 + fbq;
  const int f = fb & 15, b = fb >> 4;
  const int gq = gang >> 1, ch = gang & 1;
  const int c0 = gq * 32;

  const int t = threadIdx.x;
  const int lane = t & 63, wv = t >> 6;
  const int quad = lane >> 4, nn = lane & 15;

  for (int i = t; i < HID; i += 256) {
    float iv = g2[i] * rsqrtf(v2[i] + EPSV);
    iv2s[i] = iv;
    sh2s[i] = b2v[i] - m2[i] * iv;
  }

  float iv3[2][4], sh3[2][4];
#pragma unroll
  for (int cot = 0; cot < 2; ++cot)
#pragma unroll
    for (int jj = 0; jj < 4; ++jj) {
      int co = ch * 32 + cot * 16 + quad * 4 + jj;
      float iv = g3[co] * rsqrtf(v3[co] + EPSV);
      iv3[cot][jj] = iv;
      sh3[cot][jj] = b3v[co] - m3[co] * iv;
    }

  f32x4 acc[2][4];
#pragma unroll
  for (int cot = 0; cot < 2; ++cot)
#pragma unroll
    for (int nt = 0; nt < 4; ++nt) acc[cot][nt] = (f32x4){0.f, 0.f, 0.f, 0.f};

  const int glt = t >> 6, rt = (t >> 3) & 7, ct = t & 7;

  for (int hc = 0; hc < 12; ++hc) {
    const int hb = hc * 32;
    __syncthreads();  // prev chunk consumers done with tile/W3p/k2w/h2s

    // ---- stage h1 halo tile: 10 rows x 34 cols x 32 hid, reflect edges ----
    // 340 px x 4 sub-chunks; each iteration loads 8 bf16 (16 B) of hid.
#pragma unroll
    for (int it = 0; it < 6; ++it) {
      int idx = it * 256 + t;
      if (idx < 1360) {
        int qh = idx & 3, pxid = idx >> 2;  // 340 px
        int r = pxid / 34, col = pxid - r * 34;
        int yy = f * 8 - 1 + r;
        yy = (yy < 0) ? -yy : ((yy > 127) ? 254 - yy : yy);
        int xc = c0 - 1 + col;
        xc = (xc < 0) ? 1 : ((xc > 127) ? 126 : xc);
        uint4 v = *reinterpret_cast<const uint4*>(
            &h1T[(((size_t)b * NH + yy) * NW + xc) * HID + hb + qh * 8]);
        *reinterpret_cast<uint4*>(&tile[r][col][qh * 8]) = v;
      }
    }
    // ---- stage dw kernels (this block's 4 patches) ----
    for (int i = t; i < 288; i += 256) {
      int hh = i / 9, tap = i - hh * 9;
      const float4 wv4 = *reinterpret_cast<const float4*>(
          &w[((size_t)b * NP + N1 + (hb + hh) * 9 + tap) * 256 + f * 16 +
             gq * 4]);
      k2w[0][tap][hh] = f2bf(wv4.x);
      k2w[1][tap][hh] = f2bf(wv4.y);
      k2w[2][tap][hh] = f2bf(wv4.z);
      k2w[3][tap][hh] = f2bf(wv4.w);
    }
    // ---- stage W3 chunk as packed A-frags (hh-paired u32 writes) ----
#pragma unroll
    for (int it = 0; it < 2; ++it) {
      int i = it * 256 + t;  // 0..511
      int hhp = i & 15, co = i >> 4;
      const float* wp = &w[((size_t)b * NP + N1 + N2 + (ch * 32 + co) * HID +
                            hb + hhp * 2) * 256 + f * 16 + gq * 4];
      float4 A  = *reinterpret_cast<const float4*>(wp);
      float4 Bv = *reinterpret_cast<const float4*>(wp + 256);
      int qd = (hhp * 2) >> 3, j = (hhp * 2) & 7, cot = co >> 4;
      int cb = co & 15;
      const float* Af = (const float*)&A;
      const float* Bf = (const float*)&Bv;
#pragma unroll
      for (int k = 0; k < 4; ++k) {
        int cop = cb ^ (2 * qd) ^ k;
        *(unsigned int*)&W3p[(((k * 2 + cot) * 4 + qd) * 16 + cop) * 8 + j] =
            pack2(Af[k], Bf[k]);
      }
    }
    __syncthreads();

    // ---- dw3 + bn2 + relu6 -> h2s (thread: 1 px, 32 hids) ----
#pragma unroll
    for (int hg = 0; hg < 4; ++hg) {
      float d[8] = {0.f, 0.f, 0.f, 0.f, 0.f, 0.f, 0.f, 0.f};
#pragma unroll
      for (int dy = 0; dy < 3; ++dy)
#pragma unroll
        for (int dx = 0; dx < 3; ++dx) {
          const uint4 tv = *reinterpret_cast<const uint4*>(
              &tile[rt + dy][glt * 8 + ct + dx][hg * 8]);
          const uint4 kv =
              *reinterpret_cast<const uint4*>(&k2w[glt][dy * 3 + dx][hg * 8]);
          d[0] += ulo(tv.x) * ulo(kv.x); d[1] += uhi(tv.x) * uhi(kv.x);
          d[2] += ulo(tv.y) * ulo(kv.y); d[3] += uhi(tv.y) * uhi(kv.y);
          d[4] += ulo(tv.z) * ulo(kv.z); d[5] += uhi(tv.z) * uhi(kv.z);
          d[6] += ulo(tv.w) * ulo(kv.w); d[7] += uhi(tv.w) * uhi(kv.w);
        }
      uint4 o4;
      unsigned int op[4];
#pragma unroll
      for (int j2 = 0; j2 < 4; ++j2) {
        int ha = hb + hg * 8 + j2 * 2;
        float oa = clamp6(d[j2 * 2] * iv2s[ha] + sh2s[ha]);
        float ob = clamp6(d[j2 * 2 + 1] * iv2s[ha + 1] + sh2s[ha + 1]);
        op[j2] = (unsigned int)f2bf(oa) | ((unsigned int)f2bf(ob) << 16);
      }
      o4.x = op[0]; o4.y = op[1]; o4.z = op[2]; o4.w = op[3];
      *reinterpret_cast<uint4*>(&h2s[t][hg * 8]) = o4;
    }
    __syncthreads();

    // ---- pw2 MFMA accumulate over this 32-hid chunk (wave = patch) ----
    {
      const int gl = wv;
      const int cop = nn ^ (2 * quad) ^ gl;
      bf16x8 a0 = *reinterpret_cast<const bf16x8*>(
          &W3p[(((gl * 2 + 0) * 4 + quad) * 16 + cop) * 8]);
      bf16x8 a1 = *reinterpret_cast<const bf16x8*>(
          &W3p[(((gl * 2 + 1) * 4 + quad) * 16 + cop) * 8]);
#pragma unroll
      for (int nt = 0; nt < 4; ++nt) {
        bf16x8 bfr = *reinterpret_cast<const bf16x8*>(
            &h2s[gl * 64 + nt * 16 + nn][quad * 8]);
        acc[0][nt] = __builtin_amdgcn_mfma_f32_16x16x32_bf16(a0, bfr, acc[0][nt], 0, 0, 0);
        acc[1][nt] = __builtin_amdgcn_mfma_f32_16x16x32_bf16(a1, bfr, acc[1][nt], 0, 0, 0);
      }
    }
  }

  // ---- epilogue: bn3 + residual ----
#pragma unroll
  for (int cot = 0; cot < 2; ++cot)
#pragma unroll
    for (int nt = 0; nt < 4; ++nt) {
      int pxl = nt * 16 + nn;
      int y = f * 8 + (pxl >> 3);
      int xc = c0 + wv * 8 + (pxl & 7);
#pragma unroll
      for (int jj = 0; jj < 4; ++jj) {
        int co = ch * 32 + cot * 16 + quad * 4 + jj;
        size_t adr = ((size_t)(b * COUT + co) * NH + y) * NW + xc;
        out[adr] = acc[cot][nt][jj] * iv3[cot][jj] + sh3[cot][jj] + x[adr];
      }
    }
}

extern "C" void kernel_launch(void* const* d_in, const int* in_sizes, int n_in,
                              void* d_out, int out_size, void* d_ws,
                              size_t ws_size, hipStream_t stream) {
  (void)in_sizes; (void)n_in; (void)out_size; (void)ws_size;
  const float* x  = (const float*)d_in[0];
  const float* w  = (const float*)d_in[1];
  const float* g1 = (const float*)d_in[2];
  const float* b1 = (const float*)d_in[3];
  const float* m1 = (const float*)d_in[4];
  const float* v1 = (const float*)d_in[5];
  const float* g2 = (const float*)d_in[6];
  const float* b2 = (const float*)d_in[7];
  const float* m2 = (const float*)d_in[8];
  const float* v2 = (const float*)d_in[9];
  const float* g3 = (const float*)d_in[10];
  const float* b3 = (const float*)d_in[11];
  const float* m3 = (const float*)d_in[12];
  const float* v3 = (const float*)d_in[13];
  float* out = (float*)d_out;
  unsigned short* h1T = (unsigned short*)d_ws;  // [b][y][x][hid] bf16, 50.3 MB
  unsigned short* xT = (unsigned short*)d_out;  // [b][y][x][c] bf16, 8.4 MB
                                                // (scratch; K2 overwrites out)

  k0_transpose<<<dim3(2, 128, 4), 256, 0, stream>>>(x, xT);
  k1_pw1<<<dim3(1536), 256, 0, stream>>>(w, xT, g1, b1, m1, v1, h1T);
  k2_fused<<<dim3(512), 256, 0, stream>>>(x, w, g2, b2, m2, v2, g3, b3, m3, v3,
                                          h1T, out);
}